// Round 5
// baseline (1137.473 us; speedup 1.0000x reference)
//
#include <hip/hip_runtime.h>
#include <math.h>

// Problem constants (fixed shapes from setup_inputs)
#define Bn 32
#define TT 512
#define TM 2048
#define DD 512
#define MMp 80
#define NEGF (-1.0e9f)

// d_out layout: [h_expanded 32*2048*512][dur_loss 1][durations 32*512], all float32
constexpr size_t LOSS_OFF = (size_t)Bn * TM * DD;          // 33554432
constexpr size_t DUR_OFF  = LOSS_OFF + 1;                  // 33554433

// ---------------------------------------------------------------------------
// K0: build wTx[96][512]: rows 0..79 = w_proj^T, row 80 = b_proj, 81..95 = 0
// ---------------------------------------------------------------------------
__global__ __launch_bounds__(256) void k0_wtx(const float* __restrict__ w,
                                              const float* __restrict__ bias,
                                              float* __restrict__ wTx) {
    int m = blockIdx.x;
    for (int d = threadIdx.x; d < DD; d += 256) {
        float v = 0.f;
        if (m < 80) v = w[d * 80 + m];
        else if (m == 80) v = bias[d];
        wTx[m * DD + d] = v;
    }
}

// ---------------------------------------------------------------------------
// K1: hwX[b][m][i] = sum_d h_text[b][i][d] * wTx[m][d]   (m<96, row80 = h.b)
// ---------------------------------------------------------------------------
__global__ __launch_bounds__(256) void k1_hw(const float* __restrict__ h_text,
                                             const float* __restrict__ wTx,
                                             float* __restrict__ hwX) {
    int bid = blockIdx.x;
    int b = bid >> 3;
    int i0 = (bid & 7) * 64;
    int t = threadIdx.x;
    int tr = t & 15, tc = t >> 4;
    __shared__ __align__(16) float Asub[64 * 68];
    __shared__ __align__(16) float Bsub[96 * 68];
    float acc[4][6];
#pragma unroll
    for (int a = 0; a < 4; ++a)
#pragma unroll
        for (int c = 0; c < 6; ++c) acc[a][c] = 0.f;

    for (int d0 = 0; d0 < DD; d0 += 64) {
        __syncthreads();
#pragma unroll
        for (int p = 0; p < 4; ++p) {
            int lin = p * 256 + t;              // 0..1023
            int r = lin >> 4, dq = lin & 15;
            *(float4*)&Asub[r * 68 + dq * 4] =
                *(const float4*)&h_text[((size_t)(b * TT + i0 + r)) * DD + d0 + dq * 4];
        }
#pragma unroll
        for (int p = 0; p < 6; ++p) {
            int lin = p * 256 + t;              // 0..1535
            int cc = lin >> 4, dq = lin & 15;
            *(float4*)&Bsub[cc * 68 + dq * 4] =
                *(const float4*)&wTx[(size_t)cc * DD + d0 + dq * 4];
        }
        __syncthreads();
#pragma unroll
        for (int dd = 0; dd < 16; ++dd) {
            float4 a[4], bb[6];
#pragma unroll
            for (int ri = 0; ri < 4; ++ri)
                a[ri] = *(const float4*)&Asub[(tr * 4 + ri) * 68 + dd * 4];
#pragma unroll
            for (int ci = 0; ci < 6; ++ci)
                bb[ci] = *(const float4*)&Bsub[(tc * 6 + ci) * 68 + dd * 4];
#pragma unroll
            for (int ri = 0; ri < 4; ++ri)
#pragma unroll
                for (int ci = 0; ci < 6; ++ci) {
                    acc[ri][ci] += a[ri].x * bb[ci].x;
                    acc[ri][ci] += a[ri].y * bb[ci].y;
                    acc[ri][ci] += a[ri].z * bb[ci].z;
                    acc[ri][ci] += a[ri].w * bb[ci].w;
                }
        }
    }
#pragma unroll
    for (int ri = 0; ri < 4; ++ri)
#pragma unroll
        for (int ci = 0; ci < 6; ++ci)
            hwX[((size_t)b * 96 + tc * 6 + ci) * DD + i0 + tr * 4 + ri] = acc[ri][ci];
}

// ---------------------------------------------------------------------------
// K2: attn + masked log_softmax over text axis, written transposed:
//   logpT[b][j][i]
// ---------------------------------------------------------------------------
__global__ __launch_bounds__(256) void k2_attn(const float* __restrict__ hwX,
                                               const float* __restrict__ mel,
                                               const int* __restrict__ tlen,
                                               const int* __restrict__ mlen,
                                               float* __restrict__ logpT) {
    const int b = blockIdx.y;
    const int ml = mlen[b];
    const int j0 = blockIdx.x * 32;
    if (j0 >= ml) return;
    const int tl = tlen[b];
    const int tid = threadIdx.x;
    const int ig = tid >> 2;   // 64 i-groups, 8 rows each
    const int jg = tid & 3;    // 4 j-groups, 8 cols each

    __shared__ __align__(16) float hwS[16 * 512];
    __shared__ __align__(16) float melS[16 * 32];
    __shared__ float red[32 * 64];
    __shared__ float colmax[32];
    __shared__ float lsum[32];

    float acc[8][8];
#pragma unroll
    for (int a = 0; a < 8; ++a)
#pragma unroll
        for (int c = 0; c < 8; ++c) acc[a][c] = 0.f;

    for (int mc = 0; mc < 80; mc += 16) {
        __syncthreads();
#pragma unroll
        for (int p = 0; p < 8; ++p) {
            int lin = p * 256 + tid;            // 0..2047 float4s
            int mm = lin >> 7, iq = lin & 127;
            *(float4*)&hwS[mm * 512 + iq * 4] =
                *(const float4*)&hwX[((size_t)b * 96 + mc + mm) * DD + iq * 4];
        }
#pragma unroll
        for (int p = 0; p < 2; ++p) {
            int lin = p * 256 + tid;            // 0..511
            int mm = lin >> 5, jj = lin & 31;
            melS[lin] = mel[((size_t)b * 80 + mc + mm) * TM + j0 + jj];
        }
        __syncthreads();
#pragma unroll
        for (int mm = 0; mm < 16; ++mm) {
            float4 a0 = *(const float4*)&hwS[mm * 512 + ig * 8];
            float4 a1 = *(const float4*)&hwS[mm * 512 + ig * 8 + 4];
            float4 b0 = *(const float4*)&melS[mm * 32 + jg * 8];
            float4 b1 = *(const float4*)&melS[mm * 32 + jg * 8 + 4];
            float av[8] = {a0.x, a0.y, a0.z, a0.w, a1.x, a1.y, a1.z, a1.w};
            float bv[8] = {b0.x, b0.y, b0.z, b0.w, b1.x, b1.y, b1.z, b1.w};
#pragma unroll
            for (int ii = 0; ii < 8; ++ii)
#pragma unroll
                for (int jj = 0; jj < 8; ++jj) acc[ii][jj] += av[ii] * bv[jj];
        }
    }
    float4 h0 = *(const float4*)&hwX[((size_t)b * 96 + 80) * DD + ig * 8];
    float4 h1 = *(const float4*)&hwX[((size_t)b * 96 + 80) * DD + ig * 8 + 4];
    float hb[8] = {h0.x, h0.y, h0.z, h0.w, h1.x, h1.y, h1.z, h1.w};
#pragma unroll
    for (int ii = 0; ii < 8; ++ii) {
        bool valid = (ig * 8 + ii) < tl;
#pragma unroll
        for (int jj = 0; jj < 8; ++jj)
            acc[ii][jj] = valid ? (acc[ii][jj] + hb[ii]) : NEGF;
    }
    __syncthreads();
#pragma unroll
    for (int jj = 0; jj < 8; ++jj) {
        float m = acc[0][jj];
#pragma unroll
        for (int ii = 1; ii < 8; ++ii) m = fmaxf(m, acc[ii][jj]);
        red[(jg * 8 + jj) * 64 + ig] = m;
    }
    __syncthreads();
    if (tid < 32) {
        float m = red[tid * 64];
        for (int g = 1; g < 64; ++g) m = fmaxf(m, red[tid * 64 + g]);
        colmax[tid] = m;
    }
    __syncthreads();
#pragma unroll
    for (int jj = 0; jj < 8; ++jj) {
        float cm = colmax[jg * 8 + jj];
        float s = 0.f;
#pragma unroll
        for (int ii = 0; ii < 8; ++ii) s += expf(acc[ii][jj] - cm);
        red[(jg * 8 + jj) * 64 + ig] = s;
    }
    __syncthreads();
    if (tid < 32) {
        float s = 0.f;
        for (int g = 0; g < 64; ++g) s += red[tid * 64 + g];
        lsum[tid] = logf(s);
    }
    __syncthreads();
#pragma unroll
    for (int jj = 0; jj < 8; ++jj) {
        int j = j0 + jg * 8 + jj;
        if (j < ml) {
            float cm = colmax[jg * 8 + jj], ls = lsum[jg * 8 + jj];
            float o[8];
#pragma unroll
            for (int ii = 0; ii < 8; ++ii) {
                int i = ig * 8 + ii;
                o[ii] = (i < tl) ? ((acc[ii][jj] - cm) - ls) : NEGF;
            }
            float* dst = &logpT[((size_t)b * TM + j) * TT + ig * 8];
            *(float4*)dst = make_float4(o[0], o[1], o[2], o[3]);
            *(float4*)(dst + 4) = make_float4(o[4], o[5], o[6], o[7]);
        }
    }
}

// ---------------------------------------------------------------------------
// K3 (r5): producer/consumer wave specialization.
// Block = 16 waves. Wave 0 = DP consumer (never reads global for logp).
// Waves 1..15 = producers staging columns into a 24-slot LDS ring (2 cols
// per iteration -> ~60 outstanding dwordx4 per CU; the single-wave MLP
// ceiling measured in r2-r4 (~4 B/cyc) is bypassed via TLP).
// Ring layout is TRANSPOSED per column: element i at word (i&7)*64 + (i>>3),
// so producer ds_writes and consumer ds_reads are 2-way bank aliased = free.
// Sync: flags[slot] = ready column (producer: data writes, lgkmcnt(0), flag);
// consumed = last column the consumer finished (gates slot reuse).
// Consumer runs a 2-column software pipeline: issue col c+1's 8 ds_read_b32,
// compute col c's DP (compiler emits lgkmcnt(8) so reads overlap VALU).
// ---------------------------------------------------------------------------
#define RING 24

#define WAITLGKM asm volatile("s_waitcnt lgkmcnt(0)" ::: "memory")

// lane l gets src from lane l-1; lane 0 gets `old` (bound_ctrl=false).
__device__ __forceinline__ float dpp_shr1(float old, float src) {
    return __int_as_float(__builtin_amdgcn_update_dpp(
        __float_as_int(old), __float_as_int(src), 0x138, 0xF, 0xF, false));
}

__global__ __launch_bounds__(1024, 1) void k3_dp(const float* __restrict__ logpT,
                                                 const int* __restrict__ tlen,
                                                 const int* __restrict__ mlen,
                                                 unsigned* __restrict__ gwords,
                                                 int* __restrict__ idxmap,
                                                 float* __restrict__ dOut) {
    const int b = blockIdx.x;
    const int tid = threadIdx.x;
    const int wid = tid >> 6;
    const int lane = tid & 63;
    const int tl = tlen[b];
    const int ml = mlen[b];

    __shared__ __align__(16) float ring[RING * 512];   // 48 KB
    __shared__ int flags[RING];
    __shared__ int consumed;
    __shared__ int durs[TT];

    for (int x = tid; x < TT; x += 1024) durs[x] = 0;
    if (tid < RING) flags[tid] = -1;
    if (tid == 0) consumed = 0;
    __syncthreads();

    const float* colbase = logpT + (size_t)b * TM * TT;
    unsigned* gwb = gwords + (size_t)b * TT * 64;
    volatile int* vflags = flags;
    volatile int* vcons = &consumed;

    if (wid == 0) {
        // ================= consumer: the sequential DP =================
        float q[8];
        unsigned accb[8];
#pragma unroll
        for (int k = 0; k < 8; ++k) { q[k] = NEGF; accb[k] = 0u; }
        if (lane == 0) q[0] = colbase[0];      // logp[b][j=0][i=0]
        unsigned* gp = gwb + lane * 8 * 64;    // choice-bit flush cursor

        auto poll = [&](int slot, int c) {
            if (vflags[slot] != c) {
                while (vflags[slot] != c) __builtin_amdgcn_s_sleep(1);
            }
            asm volatile("" ::: "memory");
        };
        auto issue8 = [&](float* dst, int slot) {
            const float* rs = &ring[slot * 512];
#pragma unroll
            for (int k = 0; k < 8; ++k) dst[k] = rs[k * 64 + lane];
        };
        auto dpstep = [&](const float* lp, int c) {
            float nb[8];
            nb[0] = dpp_shr1(NEGF, q[7]);      // lane 0 -> NEGF
#pragma unroll
            for (int k = 1; k < 8; ++k) nb[k] = q[k - 1];
            const unsigned m32 = 1u << (c & 31);
#pragma unroll
            for (int k = 0; k < 8; ++k) {
                if (nb[k] > q[k]) accb[k] |= m32;    // take_diag = q_shift > q
                q[k] = lp[k] + fmaxf(q[k], nb[k]);
            }
            if ((c & 31) == 31) {              // word complete (uniform)
#pragma unroll
                for (int k = 0; k < 8; ++k) { gp[k * 64] = accb[k]; accb[k] = 0u; }
                gp += 1;
            }
        };

        float lpA[8], lpB[8];
        int sRead = 1;                         // slot of next column to read
        poll(sRead, 1); issue8(lpA, sRead);
        sRead = (sRead + 1 == RING) ? 0 : sRead + 1;
        for (int c = 1; c <= TM - 3; c += 2) {
            poll(sRead, c + 1); issue8(lpB, sRead);
            sRead = (sRead + 1 == RING) ? 0 : sRead + 1;
            dpstep(lpA, c);
            asm volatile("" ::: "memory");
            *vcons = c;
            if (c + 2 < TM) {
                poll(sRead, c + 2); issue8(lpA, sRead);
                sRead = (sRead + 1 == RING) ? 0 : sRead + 1;
            }
            dpstep(lpB, c + 1);
            asm volatile("" ::: "memory");
            *vcons = c + 1;
        }
        dpstep(lpA, TM - 1);                   // c = 2047, flushes word 63
    } else {
        // ================= producers: stage columns 1..2047 =================
        const int pp = wid - 1;                // 0..14
        for (int c0 = 1 + pp * 2; c0 < TM; c0 += 30) {
            const int c1 = c0 + 1;
            const bool two = (c1 < TM);
            const int far = two ? c1 : c0;
            const int gate = far - RING;       // slot reuse: need consumed >= gate
            if (*vcons < gate) {
                while (*vcons < gate) __builtin_amdgcn_s_sleep(2);
            }
            asm volatile("" ::: "memory");
            const float4* g0 = (const float4*)(colbase + (size_t)c0 * 512) + lane * 2;
            float4 a0 = g0[0], a1 = g0[1];
            const float4* g1 = (const float4*)(colbase + (size_t)far * 512) + lane * 2;
            float4 b0 = g1[0], b1 = g1[1];
            const int s0 = c0 % RING;
            float* r0 = &ring[s0 * 512];
            r0[lane]       = a0.x; r0[lane + 64]  = a0.y;
            r0[lane + 128] = a0.z; r0[lane + 192] = a0.w;
            r0[lane + 256] = a1.x; r0[lane + 320] = a1.y;
            r0[lane + 384] = a1.z; r0[lane + 448] = a1.w;
            int s1 = s0;
            if (two) {
                s1 = c1 % RING;
                float* r1 = &ring[s1 * 512];
                r1[lane]       = b0.x; r1[lane + 64]  = b0.y;
                r1[lane + 128] = b0.z; r1[lane + 192] = b0.w;
                r1[lane + 256] = b1.x; r1[lane + 320] = b1.y;
                r1[lane + 384] = b1.z; r1[lane + 448] = b1.w;
            }
            WAITLGKM;                          // data visible before flag
            vflags[s0] = c0;
            if (two) vflags[s1] = c1;
        }
    }
    __syncthreads();

    // ---- wave-parallel backtrack (wave 0): lane = word index in a row ----
    if (wid == 0) {
        int i = tl - 1;
        int j = ml - 1;
        unsigned r0, r1, r2, r3, r4, r5, r6, r7;   // 8-deep row shift register
        {
            int a0 = tl - 1, a1 = tl - 2, a2 = tl - 3, a3 = tl - 4;
            int a4 = tl - 5, a5 = tl - 6, a6 = tl - 7, a7 = tl - 8;
            a1 = a1 < 0 ? 0 : a1; a2 = a2 < 0 ? 0 : a2; a3 = a3 < 0 ? 0 : a3;
            a4 = a4 < 0 ? 0 : a4; a5 = a5 < 0 ? 0 : a5; a6 = a6 < 0 ? 0 : a6;
            a7 = a7 < 0 ? 0 : a7;
            r0 = gwb[a0 * 64 + lane]; r1 = gwb[a1 * 64 + lane];
            r2 = gwb[a2 * 64 + lane]; r3 = gwb[a3 * 64 + lane];
            r4 = gwb[a4 * 64 + lane]; r5 = gwb[a5 * 64 + lane];
            r6 = gwb[a6 * 64 + lane]; r7 = gwb[a7 * 64 + lane];
        }
        int nf = tl - 9;
        int guard = TT + 2;
        while (guard-- > 0) {
            unsigned w = r0;
            r0 = r1; r1 = r2; r2 = r3; r3 = r4; r4 = r5; r5 = r6; r6 = r7;
            {
                int rf = (nf < 0) ? 0 : nf;
                r7 = gwb[rf * 64 + lane];
                --nf;
            }
            int jw = j >> 5, rr = j & 31;
            unsigned topmask = (rr == 31) ? 0xFFFFFFFFu : ((1u << (rr + 1)) - 1u);
            unsigned wm = (lane < jw) ? w : ((lane == jw) ? (w & topmask) : 0u);
            unsigned long long bal = __ballot(wm != 0u);
            if (bal == 0ull) {                 // no transition: row i covers 0..j
                if (lane == 0) durs[i] = j + 1;
                break;
            }
            int hl = 63 - __clzll(bal);        // highest word with a bit
            unsigned whl = (unsigned)__builtin_amdgcn_readlane((int)wm, hl);
            int jp = (hl << 5) + (31 - __clz(whl));   // largest set bit <= j
            if (lane == 0) durs[i] = j - jp + 1;
            j = jp - 1;
            if (--i < 0) break;
        }
    }
    __syncthreads();

    // ---- durations -> d_out; exclusive cumsum -> idxmap scatter (wave 0) ----
    if (wid == 0) {
        int d[8], pre[8];
        int run = 0;
#pragma unroll
        for (int k = 0; k < 8; ++k) { d[k] = durs[lane * 8 + k]; pre[k] = run; run += d[k]; }
        int v = run;
#pragma unroll
        for (int off = 1; off < 64; off <<= 1) {
            int n = __shfl_up(v, off);
            if (lane >= off) v += n;
        }
        int base = v - run;
#pragma unroll
        for (int k = 0; k < 8; ++k) {
            int i = lane * 8 + k;
            dOut[DUR_OFF + (size_t)b * TT + i] = (float)d[k];
            int st = base + pre[k];
            for (int t2 = 0; t2 < d[k]; ++t2) idxmap[b * TM + st + t2] = i;
        }
    }
}

// ---------------------------------------------------------------------------
// K4: length-regulate expansion. One block per output row (b, j).
// ---------------------------------------------------------------------------
__global__ __launch_bounds__(128) void k4_expand(const float* __restrict__ h_text,
                                                 const int* __restrict__ idxmap,
                                                 const int* __restrict__ mlen,
                                                 float* __restrict__ dOut) {
    int bid = blockIdx.x;
    int b = bid >> 11;
    int j = bid & (TM - 1);
    int t = threadIdx.x;
    float4* orow = (float4*)dOut + (size_t)bid * 128;
    if (j < mlen[b]) {
        int i = idxmap[bid];
        const float4* hrow = (const float4*)h_text + ((size_t)(b * TT + i)) * 128;
        orow[t] = hrow[t];
    } else {
        orow[t] = make_float4(0.f, 0.f, 0.f, 0.f);
    }
}

// ---------------------------------------------------------------------------
// K5: masked sum-MSE duration loss
// ---------------------------------------------------------------------------
__global__ __launch_bounds__(256) void k5_loss(const float* __restrict__ pred,
                                               const int* __restrict__ tlen,
                                               float* __restrict__ dOut) {
    __shared__ float rs[256];
    __shared__ int rc[256];
    int t = threadIdx.x;
    float s = 0.f;
    int c = 0;
    for (int idx = t; idx < Bn * TT; idx += 256) {
        int b = idx >> 9, i = idx & 511;
        if (i < tlen[b]) {
            float dv = dOut[DUR_OFF + idx];
            float lg = logf(fmaxf(dv, 1.0f));
            float df = pred[idx] - lg;
            s += df * df;
            c += 1;
        }
    }
    rs[t] = s; rc[t] = c;
    __syncthreads();
    for (int off = 128; off > 0; off >>= 1) {
        if (t < off) { rs[t] += rs[t + off]; rc[t] += rc[t + off]; }
        __syncthreads();
    }
    if (t == 0) dOut[LOSS_OFF] = rs[0] / (float)rc[0];
}

// ---------------------------------------------------------------------------
extern "C" void kernel_launch(void* const* d_in, const int* in_sizes, int n_in,
                              void* d_out, int out_size, void* d_ws, size_t ws_size,
                              hipStream_t stream) {
    const float* h_text = (const float*)d_in[0];
    const float* mel    = (const float*)d_in[1];
    const int*   tlen   = (const int*)d_in[2];
    const int*   mlen   = (const int*)d_in[3];
    const float* w      = (const float*)d_in[4];
    const float* bias   = (const float*)d_in[5];
    const float* pred   = (const float*)d_in[6];
    float* out = (float*)d_out;

    // workspace carve-up (~138.5 MB)
    float*    logpT  = (float*)d_ws;                              // 32*2048*512 f32 (128 MB)
    float*    hwX    = logpT + (size_t)Bn * TM * TT;              // 32*96*512 f32
    float*    wTx    = hwX + (size_t)Bn * 96 * DD;                // 96*512 f32
    unsigned* gwords = (unsigned*)(wTx + 96 * DD);                // 32*512*64 u32 (4 MB)
    int*      idxmap = (int*)(gwords + (size_t)Bn * TT * 64);     // 32*2048 i32

    k0_wtx<<<dim3(96), dim3(256), 0, stream>>>(w, bias, wTx);
    k1_hw<<<dim3(256), dim3(256), 0, stream>>>(h_text, wTx, hwX);
    k2_attn<<<dim3(64, 32), dim3(256), 0, stream>>>(hwX, mel, tlen, mlen, logpT);
    k3_dp<<<dim3(32), dim3(1024), 0, stream>>>(logpT, tlen, mlen, gwords, idxmap, out);
    k4_expand<<<dim3(Bn * TM), dim3(128), 0, stream>>>(h_text, idxmap, mlen, out);
    k5_loss<<<dim3(1), dim3(256), 0, stream>>>(pred, tlen, out);
}

// Round 6
// 879.798 us; speedup vs baseline: 1.2929x; 1.2929x over previous
//
#include <hip/hip_runtime.h>
#include <math.h>

// Problem constants (fixed shapes from setup_inputs)
#define Bn 32
#define TT 512
#define TM 2048
#define DD 512
#define MMp 80
#define NEGF (-1.0e9f)

// d_out layout: [h_expanded 32*2048*512][dur_loss 1][durations 32*512], all float32
constexpr size_t LOSS_OFF = (size_t)Bn * TM * DD;          // 33554432
constexpr size_t DUR_OFF  = LOSS_OFF + 1;                  // 33554433

// ---------------------------------------------------------------------------
// K0: build wTx[96][512]: rows 0..79 = w_proj^T, row 80 = b_proj, 81..95 = 0
// ---------------------------------------------------------------------------
__global__ __launch_bounds__(256) void k0_wtx(const float* __restrict__ w,
                                              const float* __restrict__ bias,
                                              float* __restrict__ wTx) {
    int m = blockIdx.x;
    for (int d = threadIdx.x; d < DD; d += 256) {
        float v = 0.f;
        if (m < 80) v = w[d * 80 + m];
        else if (m == 80) v = bias[d];
        wTx[m * DD + d] = v;
    }
}

// ---------------------------------------------------------------------------
// K1: hwX[b][m][i] = sum_d h_text[b][i][d] * wTx[m][d]   (m<96, row80 = h.b)
// ---------------------------------------------------------------------------
__global__ __launch_bounds__(256) void k1_hw(const float* __restrict__ h_text,
                                             const float* __restrict__ wTx,
                                             float* __restrict__ hwX) {
    int bid = blockIdx.x;
    int b = bid >> 3;
    int i0 = (bid & 7) * 64;
    int t = threadIdx.x;
    int tr = t & 15, tc = t >> 4;
    __shared__ __align__(16) float Asub[64 * 68];
    __shared__ __align__(16) float Bsub[96 * 68];
    float acc[4][6];
#pragma unroll
    for (int a = 0; a < 4; ++a)
#pragma unroll
        for (int c = 0; c < 6; ++c) acc[a][c] = 0.f;

    for (int d0 = 0; d0 < DD; d0 += 64) {
        __syncthreads();
#pragma unroll
        for (int p = 0; p < 4; ++p) {
            int lin = p * 256 + t;              // 0..1023
            int r = lin >> 4, dq = lin & 15;
            *(float4*)&Asub[r * 68 + dq * 4] =
                *(const float4*)&h_text[((size_t)(b * TT + i0 + r)) * DD + d0 + dq * 4];
        }
#pragma unroll
        for (int p = 0; p < 6; ++p) {
            int lin = p * 256 + t;              // 0..1535
            int cc = lin >> 4, dq = lin & 15;
            *(float4*)&Bsub[cc * 68 + dq * 4] =
                *(const float4*)&wTx[(size_t)cc * DD + d0 + dq * 4];
        }
        __syncthreads();
#pragma unroll
        for (int dd = 0; dd < 16; ++dd) {
            float4 a[4], bb[6];
#pragma unroll
            for (int ri = 0; ri < 4; ++ri)
                a[ri] = *(const float4*)&Asub[(tr * 4 + ri) * 68 + dd * 4];
#pragma unroll
            for (int ci = 0; ci < 6; ++ci)
                bb[ci] = *(const float4*)&Bsub[(tc * 6 + ci) * 68 + dd * 4];
#pragma unroll
            for (int ri = 0; ri < 4; ++ri)
#pragma unroll
                for (int ci = 0; ci < 6; ++ci) {
                    acc[ri][ci] += a[ri].x * bb[ci].x;
                    acc[ri][ci] += a[ri].y * bb[ci].y;
                    acc[ri][ci] += a[ri].z * bb[ci].z;
                    acc[ri][ci] += a[ri].w * bb[ci].w;
                }
        }
    }
#pragma unroll
    for (int ri = 0; ri < 4; ++ri)
#pragma unroll
        for (int ci = 0; ci < 6; ++ci)
            hwX[((size_t)b * 96 + tc * 6 + ci) * DD + i0 + tr * 4 + ri] = acc[ri][ci];
}

// ---------------------------------------------------------------------------
// K2: attn + masked log_softmax over text axis, written transposed:
//   logpT[b][j][i]
// ---------------------------------------------------------------------------
__global__ __launch_bounds__(256) void k2_attn(const float* __restrict__ hwX,
                                               const float* __restrict__ mel,
                                               const int* __restrict__ tlen,
                                               const int* __restrict__ mlen,
                                               float* __restrict__ logpT) {
    const int b = blockIdx.y;
    const int ml = mlen[b];
    const int j0 = blockIdx.x * 32;
    if (j0 >= ml) return;
    const int tl = tlen[b];
    const int tid = threadIdx.x;
    const int ig = tid >> 2;   // 64 i-groups, 8 rows each
    const int jg = tid & 3;    // 4 j-groups, 8 cols each

    __shared__ __align__(16) float hwS[16 * 512];
    __shared__ __align__(16) float melS[16 * 32];
    __shared__ float red[32 * 64];
    __shared__ float colmax[32];
    __shared__ float lsum[32];

    float acc[8][8];
#pragma unroll
    for (int a = 0; a < 8; ++a)
#pragma unroll
        for (int c = 0; c < 8; ++c) acc[a][c] = 0.f;

    for (int mc = 0; mc < 80; mc += 16) {
        __syncthreads();
#pragma unroll
        for (int p = 0; p < 8; ++p) {
            int lin = p * 256 + tid;            // 0..2047 float4s
            int mm = lin >> 7, iq = lin & 127;
            *(float4*)&hwS[mm * 512 + iq * 4] =
                *(const float4*)&hwX[((size_t)b * 96 + mc + mm) * DD + iq * 4];
        }
#pragma unroll
        for (int p = 0; p < 2; ++p) {
            int lin = p * 256 + tid;            // 0..511
            int mm = lin >> 5, jj = lin & 31;
            melS[lin] = mel[((size_t)b * 80 + mc + mm) * TM + j0 + jj];
        }
        __syncthreads();
#pragma unroll
        for (int mm = 0; mm < 16; ++mm) {
            float4 a0 = *(const float4*)&hwS[mm * 512 + ig * 8];
            float4 a1 = *(const float4*)&hwS[mm * 512 + ig * 8 + 4];
            float4 b0 = *(const float4*)&melS[mm * 32 + jg * 8];
            float4 b1 = *(const float4*)&melS[mm * 32 + jg * 8 + 4];
            float av[8] = {a0.x, a0.y, a0.z, a0.w, a1.x, a1.y, a1.z, a1.w};
            float bv[8] = {b0.x, b0.y, b0.z, b0.w, b1.x, b1.y, b1.z, b1.w};
#pragma unroll
            for (int ii = 0; ii < 8; ++ii)
#pragma unroll
                for (int jj = 0; jj < 8; ++jj) acc[ii][jj] += av[ii] * bv[jj];
        }
    }
    float4 h0 = *(const float4*)&hwX[((size_t)b * 96 + 80) * DD + ig * 8];
    float4 h1 = *(const float4*)&hwX[((size_t)b * 96 + 80) * DD + ig * 8 + 4];
    float hb[8] = {h0.x, h0.y, h0.z, h0.w, h1.x, h1.y, h1.z, h1.w};
#pragma unroll
    for (int ii = 0; ii < 8; ++ii) {
        bool valid = (ig * 8 + ii) < tl;
#pragma unroll
        for (int jj = 0; jj < 8; ++jj)
            acc[ii][jj] = valid ? (acc[ii][jj] + hb[ii]) : NEGF;
    }
    __syncthreads();
#pragma unroll
    for (int jj = 0; jj < 8; ++jj) {
        float m = acc[0][jj];
#pragma unroll
        for (int ii = 1; ii < 8; ++ii) m = fmaxf(m, acc[ii][jj]);
        red[(jg * 8 + jj) * 64 + ig] = m;
    }
    __syncthreads();
    if (tid < 32) {
        float m = red[tid * 64];
        for (int g = 1; g < 64; ++g) m = fmaxf(m, red[tid * 64 + g]);
        colmax[tid] = m;
    }
    __syncthreads();
#pragma unroll
    for (int jj = 0; jj < 8; ++jj) {
        float cm = colmax[jg * 8 + jj];
        float s = 0.f;
#pragma unroll
        for (int ii = 0; ii < 8; ++ii) s += expf(acc[ii][jj] - cm);
        red[(jg * 8 + jj) * 64 + ig] = s;
    }
    __syncthreads();
    if (tid < 32) {
        float s = 0.f;
        for (int g = 0; g < 64; ++g) s += red[tid * 64 + g];
        lsum[tid] = logf(s);
    }
    __syncthreads();
#pragma unroll
    for (int jj = 0; jj < 8; ++jj) {
        int j = j0 + jg * 8 + jj;
        if (j < ml) {
            float cm = colmax[jg * 8 + jj], ls = lsum[jg * 8 + jj];
            float o[8];
#pragma unroll
            for (int ii = 0; ii < 8; ++ii) {
                int i = ig * 8 + ii;
                o[ii] = (i < tl) ? ((acc[ii][jj] - cm) - ls) : NEGF;
            }
            float* dst = &logpT[((size_t)b * TM + j) * TT + ig * 8];
            *(float4*)dst = make_float4(o[0], o[1], o[2], o[3]);
            *(float4*)(dst + 4) = make_float4(o[4], o[5], o[6], o[7]);
        }
    }
}

// ---------------------------------------------------------------------------
// K3 (r6): producer/consumer wave specialization, chunked handshake,
// pointer-free register pipeline (r5's lambda/pointer idiom demoted the
// consumer state to scratch -> VGPR_Count 24 and ~900cyc/col; this version
// uses only float4 locals and constant-indexed fully-unrolled arrays).
// Block = 16 waves, one block per batch. Wave 0 = DP consumer; waves 1..15
// = producers. Ring = 3 chunks x 8 columns (48 KB), columns contiguous.
// Sync: flags[slot] = chunk id (producer: ds_writes, lgkmcnt(0), flag);
// consumed-chunk counter gates slot reuse (consumer writes once per chunk).
// ---------------------------------------------------------------------------
#define CH 8          // columns per chunk
#define NSLOT 3       // ring slots
#define NCHUNK 256    // chunks covering columns 1..2047 (last has 7 cols)

#define WAITLGKM asm volatile("s_waitcnt lgkmcnt(0)" ::: "memory")

// lane l gets src from lane l-1; lane 0 gets `old` (bound_ctrl=false).
__device__ __forceinline__ float dpp_shr1(float old, float src) {
    return __int_as_float(__builtin_amdgcn_update_dpp(
        __float_as_int(old), __float_as_int(src), 0x138, 0xF, 0xF, false));
}

__global__ __launch_bounds__(1024, 4) void k3_dp(const float* __restrict__ logpT,
                                                 const int* __restrict__ tlen,
                                                 const int* __restrict__ mlen,
                                                 unsigned* __restrict__ gwords,
                                                 int* __restrict__ idxmap,
                                                 float* __restrict__ dOut) {
    const int b = blockIdx.x;
    const int tid = threadIdx.x;
    const int wid = tid >> 6;
    const int lane = tid & 63;
    const int tl = tlen[b];
    const int ml = mlen[b];

    __shared__ __align__(16) float ring[NSLOT * CH * 512];   // 48 KB
    __shared__ int flags[NSLOT];
    __shared__ int consumed;
    __shared__ int durs[TT];

    for (int x = tid; x < TT; x += 1024) durs[x] = 0;
    if (tid < NSLOT) flags[tid] = -1;
    if (tid == 0) consumed = 0;
    __syncthreads();

    const float* colbase = logpT + (size_t)b * TM * TT;
    unsigned* gwb = gwords + (size_t)b * TT * 64;
    volatile int* vflags = flags;
    volatile int* vcons = &consumed;

    if (wid == 0) {
        // ================= consumer: the sequential DP =================
        float q[8];
        unsigned accb[8];
#pragma unroll
        for (int k = 0; k < 8; ++k) { q[k] = NEGF; accb[k] = 0u; }
        if (lane == 0) q[0] = colbase[0];      // logp[b][j=0][i=0]
        unsigned* gp = gwb + lane * 8 * 64;    // choice-bit flush cursor

        int c = 1;
        for (int g = 0; g < NCHUNK; ++g) {
            const int s = (g % NSLOT);
            while (vflags[s] != g) { }         // spin (steady state: already set)
            asm volatile("" ::: "memory");
            const float* cp = &ring[s * (CH * 512)];
            float4 la0 = *(const float4*)&cp[lane * 8];
            float4 la1 = *(const float4*)&cp[lane * 8 + 4];
            float4 lb0, lb1;
#pragma unroll
            for (int cc = 0; cc < CH; ++cc) {
                if (cc + 1 < CH) {             // 1-col lookahead within chunk
                    lb0 = *(const float4*)&cp[(cc + 1) * 512 + lane * 8];
                    lb1 = *(const float4*)&cp[(cc + 1) * 512 + lane * 8 + 4];
                }
                if (c < TM) {                  // uniform (last chunk has 7 cols)
                    float lp[8] = {la0.x, la0.y, la0.z, la0.w,
                                   la1.x, la1.y, la1.z, la1.w};
                    float nb[8];
                    nb[0] = dpp_shr1(NEGF, q[7]);   // lane 0 -> NEGF
#pragma unroll
                    for (int k = 1; k < 8; ++k) nb[k] = q[k - 1];
                    const unsigned m32 = 1u << (c & 31);
#pragma unroll
                    for (int k = 0; k < 8; ++k) {
                        if (nb[k] > q[k]) accb[k] |= m32;   // take_diag
                        q[k] = lp[k] + fmaxf(q[k], nb[k]);
                    }
                    if ((c & 31) == 31) {      // word complete (uniform)
#pragma unroll
                        for (int k = 0; k < 8; ++k) { gp[k * 64] = accb[k]; accb[k] = 0u; }
                        gp += 1;
                    }
                    ++c;
                }
                la0 = lb0; la1 = lb1;
            }
            asm volatile("" ::: "memory");
            *vcons = g + 1;
        }
    } else {
        // ================= producers: stage chunks of 8 columns =================
        const int pp = wid - 1;                // 0..14
        for (int g = pp; g < NCHUNK; g += 15) {
            const int cbase = 1 + g * CH;
            float4 va[CH], vb[CH];
#pragma unroll
            for (int cc = 0; cc < CH; ++cc) {  // 16 loads in flight
                int cx = cbase + cc;
                cx = (cx > TM - 1) ? (TM - 1) : cx;   // clamp dummy tail
                const float4* gsrc = (const float4*)(colbase + (size_t)cx * 512) + lane * 2;
                va[cc] = gsrc[0];
                vb[cc] = gsrc[1];
            }
            if (g >= NSLOT) {                  // gate: slot free when chunk g-NSLOT consumed
                while (*vcons < g - (NSLOT - 1)) __builtin_amdgcn_s_sleep(2);
                asm volatile("" ::: "memory");
            }
            const int s = (g % NSLOT);
            float* dst = &ring[s * (CH * 512)];
#pragma unroll
            for (int cc = 0; cc < CH; ++cc) {
                *(float4*)&dst[cc * 512 + lane * 8]     = va[cc];
                *(float4*)&dst[cc * 512 + lane * 8 + 4] = vb[cc];
            }
            WAITLGKM;                          // data visible before flag
            vflags[s] = g;
        }
    }
    __threadfence();
    __syncthreads();

    // ---- wave-parallel backtrack (wave 0): lane = word index in a row ----
    if (wid == 0) {
        int i = tl - 1;
        int j = ml - 1;
        unsigned r0, r1, r2, r3, r4, r5, r6, r7;   // 8-deep row shift register
        {
            int a0 = tl - 1, a1 = tl - 2, a2 = tl - 3, a3 = tl - 4;
            int a4 = tl - 5, a5 = tl - 6, a6 = tl - 7, a7 = tl - 8;
            a1 = a1 < 0 ? 0 : a1; a2 = a2 < 0 ? 0 : a2; a3 = a3 < 0 ? 0 : a3;
            a4 = a4 < 0 ? 0 : a4; a5 = a5 < 0 ? 0 : a5; a6 = a6 < 0 ? 0 : a6;
            a7 = a7 < 0 ? 0 : a7;
            r0 = gwb[a0 * 64 + lane]; r1 = gwb[a1 * 64 + lane];
            r2 = gwb[a2 * 64 + lane]; r3 = gwb[a3 * 64 + lane];
            r4 = gwb[a4 * 64 + lane]; r5 = gwb[a5 * 64 + lane];
            r6 = gwb[a6 * 64 + lane]; r7 = gwb[a7 * 64 + lane];
        }
        int nf = tl - 9;
        int guard = TT + 2;
        while (guard-- > 0) {
            unsigned w = r0;
            r0 = r1; r1 = r2; r2 = r3; r3 = r4; r4 = r5; r5 = r6; r6 = r7;
            {
                int rf = (nf < 0) ? 0 : nf;
                r7 = gwb[rf * 64 + lane];
                --nf;
            }
            int jw = j >> 5, rr = j & 31;
            unsigned topmask = (rr == 31) ? 0xFFFFFFFFu : ((1u << (rr + 1)) - 1u);
            unsigned wm = (lane < jw) ? w : ((lane == jw) ? (w & topmask) : 0u);
            unsigned long long bal = __ballot(wm != 0u);
            if (bal == 0ull) {                 // no transition: row i covers 0..j
                if (lane == 0) durs[i] = j + 1;
                break;
            }
            int hl = 63 - __clzll(bal);        // highest word with a bit
            unsigned whl = (unsigned)__builtin_amdgcn_readlane((int)wm, hl);
            int jp = (hl << 5) + (31 - __clz(whl));   // largest set bit <= j
            if (lane == 0) durs[i] = j - jp + 1;
            j = jp - 1;
            if (--i < 0) break;
        }
    }
    __syncthreads();

    // ---- durations -> d_out; exclusive cumsum -> idxmap scatter (wave 0) ----
    if (wid == 0) {
        int d[8], pre[8];
        int run = 0;
#pragma unroll
        for (int k = 0; k < 8; ++k) { d[k] = durs[lane * 8 + k]; pre[k] = run; run += d[k]; }
        int v = run;
#pragma unroll
        for (int off = 1; off < 64; off <<= 1) {
            int n = __shfl_up(v, off);
            if (lane >= off) v += n;
        }
        int base = v - run;
#pragma unroll
        for (int k = 0; k < 8; ++k) {
            int i = lane * 8 + k;
            dOut[DUR_OFF + (size_t)b * TT + i] = (float)d[k];
            int st = base + pre[k];
            for (int t2 = 0; t2 < d[k]; ++t2) idxmap[b * TM + st + t2] = i;
        }
    }
}

// ---------------------------------------------------------------------------
// K4: length-regulate expansion. One block per output row (b, j).
// ---------------------------------------------------------------------------
__global__ __launch_bounds__(128) void k4_expand(const float* __restrict__ h_text,
                                                 const int* __restrict__ idxmap,
                                                 const int* __restrict__ mlen,
                                                 float* __restrict__ dOut) {
    int bid = blockIdx.x;
    int b = bid >> 11;
    int j = bid & (TM - 1);
    int t = threadIdx.x;
    float4* orow = (float4*)dOut + (size_t)bid * 128;
    if (j < mlen[b]) {
        int i = idxmap[bid];
        const float4* hrow = (const float4*)h_text + ((size_t)(b * TT + i)) * 128;
        orow[t] = hrow[t];
    } else {
        orow[t] = make_float4(0.f, 0.f, 0.f, 0.f);
    }
}

// ---------------------------------------------------------------------------
// K5: masked sum-MSE duration loss
// ---------------------------------------------------------------------------
__global__ __launch_bounds__(256) void k5_loss(const float* __restrict__ pred,
                                               const int* __restrict__ tlen,
                                               float* __restrict__ dOut) {
    __shared__ float rs[256];
    __shared__ int rc[256];
    int t = threadIdx.x;
    float s = 0.f;
    int c = 0;
    for (int idx = t; idx < Bn * TT; idx += 256) {
        int b = idx >> 9, i = idx & 511;
        if (i < tlen[b]) {
            float dv = dOut[DUR_OFF + idx];
            float lg = logf(fmaxf(dv, 1.0f));
            float df = pred[idx] - lg;
            s += df * df;
            c += 1;
        }
    }
    rs[t] = s; rc[t] = c;
    __syncthreads();
    for (int off = 128; off > 0; off >>= 1) {
        if (t < off) { rs[t] += rs[t + off]; rc[t] += rc[t + off]; }
        __syncthreads();
    }
    if (t == 0) dOut[LOSS_OFF] = rs[0] / (float)rc[0];
}

// ---------------------------------------------------------------------------
extern "C" void kernel_launch(void* const* d_in, const int* in_sizes, int n_in,
                              void* d_out, int out_size, void* d_ws, size_t ws_size,
                              hipStream_t stream) {
    const float* h_text = (const float*)d_in[0];
    const float* mel    = (const float*)d_in[1];
    const int*   tlen   = (const int*)d_in[2];
    const int*   mlen   = (const int*)d_in[3];
    const float* w      = (const float*)d_in[4];
    const float* bias   = (const float*)d_in[5];
    const float* pred   = (const float*)d_in[6];
    float* out = (float*)d_out;

    // workspace carve-up (~138.5 MB)
    float*    logpT  = (float*)d_ws;                              // 32*2048*512 f32 (128 MB)
    float*    hwX    = logpT + (size_t)Bn * TM * TT;              // 32*96*512 f32
    float*    wTx    = hwX + (size_t)Bn * 96 * DD;                // 96*512 f32
    unsigned* gwords = (unsigned*)(wTx + 96 * DD);                // 32*512*64 u32 (4 MB)
    int*      idxmap = (int*)(gwords + (size_t)Bn * TT * 64);     // 32*2048 i32

    k0_wtx<<<dim3(96), dim3(256), 0, stream>>>(w, bias, wTx);
    k1_hw<<<dim3(256), dim3(256), 0, stream>>>(h_text, wTx, hwX);
    k2_attn<<<dim3(64, 32), dim3(256), 0, stream>>>(hwX, mel, tlen, mlen, logpT);
    k3_dp<<<dim3(32), dim3(1024), 0, stream>>>(logpT, tlen, mlen, gwords, idxmap, out);
    k4_expand<<<dim3(Bn * TM), dim3(128), 0, stream>>>(h_text, idxmap, mlen, out);
    k5_loss<<<dim3(1), dim3(256), 0, stream>>>(pred, tlen, out);
}

// Round 7
// 844.920 us; speedup vs baseline: 1.3462x; 1.0413x over previous
//
#include <hip/hip_runtime.h>
#include <math.h>

// Problem constants (fixed shapes from setup_inputs)
#define Bn 32
#define TT 512
#define TM 2048
#define DD 512
#define MMp 80
#define NEGF (-1.0e9f)

// d_out layout: [h_expanded 32*2048*512][dur_loss 1][durations 32*512], all float32
constexpr size_t LOSS_OFF = (size_t)Bn * TM * DD;          // 33554432
constexpr size_t DUR_OFF  = LOSS_OFF + 1;                  // 33554433

// ---------------------------------------------------------------------------
// K0: build wTx[96][512]: rows 0..79 = w_proj^T, row 80 = b_proj, 81..95 = 0
// ---------------------------------------------------------------------------
__global__ __launch_bounds__(256) void k0_wtx(const float* __restrict__ w,
                                              const float* __restrict__ bias,
                                              float* __restrict__ wTx) {
    int m = blockIdx.x;
    for (int d = threadIdx.x; d < DD; d += 256) {
        float v = 0.f;
        if (m < 80) v = w[d * 80 + m];
        else if (m == 80) v = bias[d];
        wTx[m * DD + d] = v;
    }
}

// ---------------------------------------------------------------------------
// K1: hwX[b][m][i] = sum_d h_text[b][i][d] * wTx[m][d]   (m<96, row80 = h.b)
// ---------------------------------------------------------------------------
__global__ __launch_bounds__(256) void k1_hw(const float* __restrict__ h_text,
                                             const float* __restrict__ wTx,
                                             float* __restrict__ hwX) {
    int bid = blockIdx.x;
    int b = bid >> 3;
    int i0 = (bid & 7) * 64;
    int t = threadIdx.x;
    int tr = t & 15, tc = t >> 4;
    __shared__ __align__(16) float Asub[64 * 68];
    __shared__ __align__(16) float Bsub[96 * 68];
    float acc[4][6];
#pragma unroll
    for (int a = 0; a < 4; ++a)
#pragma unroll
        for (int c = 0; c < 6; ++c) acc[a][c] = 0.f;

    for (int d0 = 0; d0 < DD; d0 += 64) {
        __syncthreads();
#pragma unroll
        for (int p = 0; p < 4; ++p) {
            int lin = p * 256 + t;              // 0..1023
            int r = lin >> 4, dq = lin & 15;
            *(float4*)&Asub[r * 68 + dq * 4] =
                *(const float4*)&h_text[((size_t)(b * TT + i0 + r)) * DD + d0 + dq * 4];
        }
#pragma unroll
        for (int p = 0; p < 6; ++p) {
            int lin = p * 256 + t;              // 0..1535
            int cc = lin >> 4, dq = lin & 15;
            *(float4*)&Bsub[cc * 68 + dq * 4] =
                *(const float4*)&wTx[(size_t)cc * DD + d0 + dq * 4];
        }
        __syncthreads();
#pragma unroll
        for (int dd = 0; dd < 16; ++dd) {
            float4 a[4], bb[6];
#pragma unroll
            for (int ri = 0; ri < 4; ++ri)
                a[ri] = *(const float4*)&Asub[(tr * 4 + ri) * 68 + dd * 4];
#pragma unroll
            for (int ci = 0; ci < 6; ++ci)
                bb[ci] = *(const float4*)&Bsub[(tc * 6 + ci) * 68 + dd * 4];
#pragma unroll
            for (int ri = 0; ri < 4; ++ri)
#pragma unroll
                for (int ci = 0; ci < 6; ++ci) {
                    acc[ri][ci] += a[ri].x * bb[ci].x;
                    acc[ri][ci] += a[ri].y * bb[ci].y;
                    acc[ri][ci] += a[ri].z * bb[ci].z;
                    acc[ri][ci] += a[ri].w * bb[ci].w;
                }
        }
    }
#pragma unroll
    for (int ri = 0; ri < 4; ++ri)
#pragma unroll
        for (int ci = 0; ci < 6; ++ci)
            hwX[((size_t)b * 96 + tc * 6 + ci) * DD + i0 + tr * 4 + ri] = acc[ri][ci];
}

// ---------------------------------------------------------------------------
// K2: attn + masked log_softmax over text axis, written transposed:
//   logpT[b][j][i]
// ---------------------------------------------------------------------------
__global__ __launch_bounds__(256) void k2_attn(const float* __restrict__ hwX,
                                               const float* __restrict__ mel,
                                               const int* __restrict__ tlen,
                                               const int* __restrict__ mlen,
                                               float* __restrict__ logpT) {
    const int b = blockIdx.y;
    const int ml = mlen[b];
    const int j0 = blockIdx.x * 32;
    if (j0 >= ml) return;
    const int tl = tlen[b];
    const int tid = threadIdx.x;
    const int ig = tid >> 2;   // 64 i-groups, 8 rows each
    const int jg = tid & 3;    // 4 j-groups, 8 cols each

    __shared__ __align__(16) float hwS[16 * 512];
    __shared__ __align__(16) float melS[16 * 32];
    __shared__ float red[32 * 64];
    __shared__ float colmax[32];
    __shared__ float lsum[32];

    float acc[8][8];
#pragma unroll
    for (int a = 0; a < 8; ++a)
#pragma unroll
        for (int c = 0; c < 8; ++c) acc[a][c] = 0.f;

    for (int mc = 0; mc < 80; mc += 16) {
        __syncthreads();
#pragma unroll
        for (int p = 0; p < 8; ++p) {
            int lin = p * 256 + tid;            // 0..2047 float4s
            int mm = lin >> 7, iq = lin & 127;
            *(float4*)&hwS[mm * 512 + iq * 4] =
                *(const float4*)&hwX[((size_t)b * 96 + mc + mm) * DD + iq * 4];
        }
#pragma unroll
        for (int p = 0; p < 2; ++p) {
            int lin = p * 256 + tid;            // 0..511
            int mm = lin >> 5, jj = lin & 31;
            melS[lin] = mel[((size_t)b * 80 + mc + mm) * TM + j0 + jj];
        }
        __syncthreads();
#pragma unroll
        for (int mm = 0; mm < 16; ++mm) {
            float4 a0 = *(const float4*)&hwS[mm * 512 + ig * 8];
            float4 a1 = *(const float4*)&hwS[mm * 512 + ig * 8 + 4];
            float4 b0 = *(const float4*)&melS[mm * 32 + jg * 8];
            float4 b1 = *(const float4*)&melS[mm * 32 + jg * 8 + 4];
            float av[8] = {a0.x, a0.y, a0.z, a0.w, a1.x, a1.y, a1.z, a1.w};
            float bv[8] = {b0.x, b0.y, b0.z, b0.w, b1.x, b1.y, b1.z, b1.w};
#pragma unroll
            for (int ii = 0; ii < 8; ++ii)
#pragma unroll
                for (int jj = 0; jj < 8; ++jj) acc[ii][jj] += av[ii] * bv[jj];
        }
    }
    float4 h0 = *(const float4*)&hwX[((size_t)b * 96 + 80) * DD + ig * 8];
    float4 h1 = *(const float4*)&hwX[((size_t)b * 96 + 80) * DD + ig * 8 + 4];
    float hb[8] = {h0.x, h0.y, h0.z, h0.w, h1.x, h1.y, h1.z, h1.w};
#pragma unroll
    for (int ii = 0; ii < 8; ++ii) {
        bool valid = (ig * 8 + ii) < tl;
#pragma unroll
        for (int jj = 0; jj < 8; ++jj)
            acc[ii][jj] = valid ? (acc[ii][jj] + hb[ii]) : NEGF;
    }
    __syncthreads();
#pragma unroll
    for (int jj = 0; jj < 8; ++jj) {
        float m = acc[0][jj];
#pragma unroll
        for (int ii = 1; ii < 8; ++ii) m = fmaxf(m, acc[ii][jj]);
        red[(jg * 8 + jj) * 64 + ig] = m;
    }
    __syncthreads();
    if (tid < 32) {
        float m = red[tid * 64];
        for (int g = 1; g < 64; ++g) m = fmaxf(m, red[tid * 64 + g]);
        colmax[tid] = m;
    }
    __syncthreads();
#pragma unroll
    for (int jj = 0; jj < 8; ++jj) {
        float cm = colmax[jg * 8 + jj];
        float s = 0.f;
#pragma unroll
        for (int ii = 0; ii < 8; ++ii) s += expf(acc[ii][jj] - cm);
        red[(jg * 8 + jj) * 64 + ig] = s;
    }
    __syncthreads();
    if (tid < 32) {
        float s = 0.f;
        for (int g = 0; g < 64; ++g) s += red[tid * 64 + g];
        lsum[tid] = logf(s);
    }
    __syncthreads();
#pragma unroll
    for (int jj = 0; jj < 8; ++jj) {
        int j = j0 + jg * 8 + jj;
        if (j < ml) {
            float cm = colmax[jg * 8 + jj], ls = lsum[jg * 8 + jj];
            float o[8];
#pragma unroll
            for (int ii = 0; ii < 8; ++ii) {
                int i = ig * 8 + ii;
                o[ii] = (i < tl) ? ((acc[ii][jj] - cm) - ls) : NEGF;
            }
            float* dst = &logpT[((size_t)b * TM + j) * TT + ig * 8];
            *(float4*)dst = make_float4(o[0], o[1], o[2], o[3]);
            *(float4*)(dst + 4) = make_float4(o[4], o[5], o[6], o[7]);
        }
    }
}

// ---------------------------------------------------------------------------
// K3 (r7): producer/consumer, spill-proof edition.
// r5/r6 lesson: 1024-thread blocks + register staging => compiler allocates
// 24-32 VGPRs and demotes local arrays to scratch (global!). Fixes:
//   - 512-thread block (8 waves: 1 consumer + 7 producers), VGPR cap 256.
//   - producers stage via global_load_lds (ZERO VGPR staging, fire+forget;
//     their vmcnt(0) drain costs nothing - producer waves are otherwise idle).
//   - consumer DP state is explicit named scalars (q0..q7, a0..a7) updated
//     in reverse-k order; no arrays, no lambdas, no pointers to locals.
// Ring: 5 slots x 6 columns (60 KB LDS). Gate distance 4 chunks (~24 cols
// ~2800 cyc of consumer buffer > ~1300 cyc producer DMA latency) => no
// steady-state stalls. flags[slot]=chunk id; consumed = chunks retired.
// ---------------------------------------------------------------------------
#define CH 6          // columns per chunk
#define NSLOT 5       // ring slots (60 KB)
#define NCHUNK 342    // ceil(2047/6); cols 1..2047, tail cols clamped/skipped

#define WAITALL  asm volatile("s_waitcnt vmcnt(0)" ::: "memory")

__device__ __forceinline__ void lds_dma16(const float* g, float* l) {
    __builtin_amdgcn_global_load_lds((const __attribute__((address_space(1))) void*)g,
                                     (__attribute__((address_space(3))) void*)l,
                                     16, 0, 0);
}

// lane l gets src from lane l-1; lane 0 gets `old` (bound_ctrl=false).
__device__ __forceinline__ float dpp_shr1(float old, float src) {
    return __int_as_float(__builtin_amdgcn_update_dpp(
        __float_as_int(old), __float_as_int(src), 0x138, 0xF, 0xF, false));
}

// One DP column, reverse-k update (nb[k]=q[k-1] must be pre-update values).
#define DPSTEP(V0,V1,V2,V3,V4,V5,V6,V7)                                   \
    do {                                                                  \
        float n0 = dpp_shr1(NEGF, q7);                                    \
        unsigned m32 = 1u << (c & 31);                                    \
        if (q6 > q7) a7 |= m32;  q7 = (V7) + fmaxf(q7, q6);               \
        if (q5 > q6) a6 |= m32;  q6 = (V6) + fmaxf(q6, q5);               \
        if (q4 > q5) a5 |= m32;  q5 = (V5) + fmaxf(q5, q4);               \
        if (q3 > q4) a4 |= m32;  q4 = (V4) + fmaxf(q4, q3);               \
        if (q2 > q3) a3 |= m32;  q3 = (V3) + fmaxf(q3, q2);               \
        if (q1 > q2) a2 |= m32;  q2 = (V2) + fmaxf(q2, q1);               \
        if (q0 > q1) a1 |= m32;  q1 = (V1) + fmaxf(q1, q0);               \
        if (n0 > q0) a0 |= m32;  q0 = (V0) + fmaxf(q0, n0);               \
        if ((c & 31) == 31) {                                             \
            gp[0]   = a0; gp[64]  = a1; gp[128] = a2; gp[192] = a3;       \
            gp[256] = a4; gp[320] = a5; gp[384] = a6; gp[448] = a7;       \
            a0 = a1 = a2 = a3 = a4 = a5 = a6 = a7 = 0u;                   \
            gp += 1;                                                      \
        }                                                                 \
    } while (0)

__global__ __launch_bounds__(512, 2) void k3_dp(const float* __restrict__ logpT,
                                                const int* __restrict__ tlen,
                                                const int* __restrict__ mlen,
                                                unsigned* __restrict__ gwords,
                                                int* __restrict__ idxmap,
                                                float* __restrict__ dOut) {
    const int b = blockIdx.x;
    const int tid = threadIdx.x;
    const int wid = tid >> 6;
    const int lane = tid & 63;
    const int tl = tlen[b];
    const int ml = mlen[b];

    __shared__ __align__(16) float ring[NSLOT * CH * 512];   // 60 KB
    __shared__ int flags[NSLOT];
    __shared__ int consumed;
    __shared__ int durs[TT];

    for (int x = tid; x < TT; x += 512) durs[x] = 0;
    if (tid < NSLOT) flags[tid] = -1;
    if (tid == 0) consumed = 0;
    __syncthreads();

    const float* colbase = logpT + (size_t)b * TM * TT;
    unsigned* gwb = gwords + (size_t)b * TT * 64;
    volatile int* vflags = flags;
    volatile int* vcons = &consumed;

    if (wid == 0) {
        // ================= consumer: the sequential DP =================
        float q0 = NEGF, q1 = NEGF, q2 = NEGF, q3 = NEGF;
        float q4 = NEGF, q5 = NEGF, q6 = NEGF, q7 = NEGF;
        unsigned a0 = 0u, a1 = 0u, a2 = 0u, a3 = 0u;
        unsigned a4 = 0u, a5 = 0u, a6 = 0u, a7 = 0u;
        if (lane == 0) q0 = colbase[0];        // logp[b][j=0][i=0]
        unsigned* gp = gwb + lane * 8 * 64;    // choice-bit flush cursor

        int c = 1;
        for (int g = 0; g < NCHUNK; ++g) {
            const int s = g % NSLOT;
            while (vflags[s] != g) { }         // steady state: already set
            asm volatile("" ::: "memory");
            const float* cp = &ring[s * (CH * 512)];
            float4 la0 = *(const float4*)&cp[lane * 8];
            float4 la1 = *(const float4*)&cp[lane * 8 + 4];
#pragma unroll
            for (int cc = 0; cc < CH; ++cc) {
                float4 nx0 = la0, nx1 = la1;
                if (cc + 1 < CH) {             // 1-col lookahead within chunk
                    nx0 = *(const float4*)&cp[(cc + 1) * 512 + lane * 8];
                    nx1 = *(const float4*)&cp[(cc + 1) * 512 + lane * 8 + 4];
                }
                if (c < TM) {                  // uniform branch (tail chunk)
                    DPSTEP(la0.x, la0.y, la0.z, la0.w, la1.x, la1.y, la1.z, la1.w);
                    ++c;
                }
                la0 = nx0; la1 = nx1;
            }
            asm volatile("" ::: "memory");
            *vcons = g + 1;
        }
    } else {
        // ===== producers: stage chunks of 6 columns via LDS-DMA (0 VGPRs) =====
        const int pp = wid - 1;                // 0..6
        for (int g = pp; g < NCHUNK; g += 7) {
            if (g >= NSLOT) {                  // slot free when chunk g-NSLOT retired
                while (*vcons < g - (NSLOT - 1)) __builtin_amdgcn_s_sleep(2);
                asm volatile("" ::: "memory");
            }
            const int s = g % NSLOT;
            float* dst = &ring[s * (CH * 512)];
            const int cbase = 1 + g * CH;
#pragma unroll
            for (int cc = 0; cc < CH; ++cc) {
                int cx = cbase + cc;
                cx = (cx > TM - 1) ? (TM - 1) : cx;   // clamp dummy tail
                const float* gsrc = colbase + (size_t)cx * 512 + lane * 4;
                lds_dma16(gsrc,       dst + cc * 512);
                lds_dma16(gsrc + 256, dst + cc * 512 + 256);
            }
            WAITALL;                           // DMA complete before flag
            vflags[s] = g;
        }
    }
    __threadfence();
    __syncthreads();

    // ---- wave-parallel backtrack (wave 0): lane = word index in a row ----
    if (wid == 0) {
        int i = tl - 1;
        int j = ml - 1;
        unsigned r0, r1, r2, r3, r4, r5, r6, r7;   // 8-deep row shift register
        {
            int b0 = tl - 1, b1 = tl - 2, b2 = tl - 3, b3 = tl - 4;
            int b4 = tl - 5, b5 = tl - 6, b6 = tl - 7, b7 = tl - 8;
            b1 = b1 < 0 ? 0 : b1; b2 = b2 < 0 ? 0 : b2; b3 = b3 < 0 ? 0 : b3;
            b4 = b4 < 0 ? 0 : b4; b5 = b5 < 0 ? 0 : b5; b6 = b6 < 0 ? 0 : b6;
            b7 = b7 < 0 ? 0 : b7;
            r0 = gwb[b0 * 64 + lane]; r1 = gwb[b1 * 64 + lane];
            r2 = gwb[b2 * 64 + lane]; r3 = gwb[b3 * 64 + lane];
            r4 = gwb[b4 * 64 + lane]; r5 = gwb[b5 * 64 + lane];
            r6 = gwb[b6 * 64 + lane]; r7 = gwb[b7 * 64 + lane];
        }
        int nf = tl - 9;
        int guard = TT + 2;
        while (guard-- > 0) {
            unsigned w = r0;
            r0 = r1; r1 = r2; r2 = r3; r3 = r4; r4 = r5; r5 = r6; r6 = r7;
            {
                int rf = (nf < 0) ? 0 : nf;
                r7 = gwb[rf * 64 + lane];
                --nf;
            }
            int jw = j >> 5, rr = j & 31;
            unsigned topmask = (rr == 31) ? 0xFFFFFFFFu : ((1u << (rr + 1)) - 1u);
            unsigned wm = (lane < jw) ? w : ((lane == jw) ? (w & topmask) : 0u);
            unsigned long long bal = __ballot(wm != 0u);
            if (bal == 0ull) {                 // no transition: row i covers 0..j
                if (lane == 0) durs[i] = j + 1;
                break;
            }
            int hl = 63 - __clzll(bal);        // highest word with a bit
            unsigned whl = (unsigned)__builtin_amdgcn_readlane((int)wm, hl);
            int jp = (hl << 5) + (31 - __clz(whl));   // largest set bit <= j
            if (lane == 0) durs[i] = j - jp + 1;
            j = jp - 1;
            if (--i < 0) break;
        }
    }
    __syncthreads();

    // ---- durations -> d_out; exclusive cumsum -> idxmap scatter (wave 0) ----
    if (wid == 0) {
        int d[8], pre[8];
        int run = 0;
#pragma unroll
        for (int k = 0; k < 8; ++k) { d[k] = durs[lane * 8 + k]; pre[k] = run; run += d[k]; }
        int v = run;
#pragma unroll
        for (int off = 1; off < 64; off <<= 1) {
            int n = __shfl_up(v, off);
            if (lane >= off) v += n;
        }
        int base = v - run;
#pragma unroll
        for (int k = 0; k < 8; ++k) {
            int i = lane * 8 + k;
            dOut[DUR_OFF + (size_t)b * TT + i] = (float)d[k];
            int st = base + pre[k];
            for (int t2 = 0; t2 < d[k]; ++t2) idxmap[b * TM + st + t2] = i;
        }
    }
}

// ---------------------------------------------------------------------------
// K4: length-regulate expansion. One block per output row (b, j).
// ---------------------------------------------------------------------------
__global__ __launch_bounds__(128) void k4_expand(const float* __restrict__ h_text,
                                                 const int* __restrict__ idxmap,
                                                 const int* __restrict__ mlen,
                                                 float* __restrict__ dOut) {
    int bid = blockIdx.x;
    int b = bid >> 11;
    int j = bid & (TM - 1);
    int t = threadIdx.x;
    float4* orow = (float4*)dOut + (size_t)bid * 128;
    if (j < mlen[b]) {
        int i = idxmap[bid];
        const float4* hrow = (const float4*)h_text + ((size_t)(b * TT + i)) * 128;
        orow[t] = hrow[t];
    } else {
        orow[t] = make_float4(0.f, 0.f, 0.f, 0.f);
    }
}

// ---------------------------------------------------------------------------
// K5: masked sum-MSE duration loss
// ---------------------------------------------------------------------------
__global__ __launch_bounds__(256) void k5_loss(const float* __restrict__ pred,
                                               const int* __restrict__ tlen,
                                               float* __restrict__ dOut) {
    __shared__ float rs[256];
    __shared__ int rc[256];
    int t = threadIdx.x;
    float s = 0.f;
    int c = 0;
    for (int idx = t; idx < Bn * TT; idx += 256) {
        int b = idx >> 9, i = idx & 511;
        if (i < tlen[b]) {
            float dv = dOut[DUR_OFF + idx];
            float lg = logf(fmaxf(dv, 1.0f));
            float df = pred[idx] - lg;
            s += df * df;
            c += 1;
        }
    }
    rs[t] = s; rc[t] = c;
    __syncthreads();
    for (int off = 128; off > 0; off >>= 1) {
        if (t < off) { rs[t] += rs[t + off]; rc[t] += rc[t + off]; }
        __syncthreads();
    }
    if (t == 0) dOut[LOSS_OFF] = rs[0] / (float)rc[0];
}

// ---------------------------------------------------------------------------
extern "C" void kernel_launch(void* const* d_in, const int* in_sizes, int n_in,
                              void* d_out, int out_size, void* d_ws, size_t ws_size,
                              hipStream_t stream) {
    const float* h_text = (const float*)d_in[0];
    const float* mel    = (const float*)d_in[1];
    const int*   tlen   = (const int*)d_in[2];
    const int*   mlen   = (const int*)d_in[3];
    const float* w      = (const float*)d_in[4];
    const float* bias   = (const float*)d_in[5];
    const float* pred   = (const float*)d_in[6];
    float* out = (float*)d_out;

    // workspace carve-up (~138.5 MB)
    float*    logpT  = (float*)d_ws;                              // 32*2048*512 f32 (128 MB)
    float*    hwX    = logpT + (size_t)Bn * TM * TT;              // 32*96*512 f32
    float*    wTx    = hwX + (size_t)Bn * 96 * DD;                // 96*512 f32
    unsigned* gwords = (unsigned*)(wTx + 96 * DD);                // 32*512*64 u32 (4 MB)
    int*      idxmap = (int*)(gwords + (size_t)Bn * TT * 64);     // 32*2048 i32

    k0_wtx<<<dim3(96), dim3(256), 0, stream>>>(w, bias, wTx);
    k1_hw<<<dim3(256), dim3(256), 0, stream>>>(h_text, wTx, hwX);
    k2_attn<<<dim3(64, 32), dim3(256), 0, stream>>>(hwX, mel, tlen, mlen, logpT);
    k3_dp<<<dim3(32), dim3(512), 0, stream>>>(logpT, tlen, mlen, gwords, idxmap, out);
    k4_expand<<<dim3(Bn * TM), dim3(128), 0, stream>>>(h_text, idxmap, mlen, out);
    k5_loss<<<dim3(1), dim3(256), 0, stream>>>(pred, tlen, out);
}